// Round 1
// baseline (431.449 us; speedup 1.0000x reference)
//
#include <hip/hip_runtime.h>

// Elementwise modified Bessel K_1(x), fp32, via A&S 9.8.7 / 9.8.8.
// Memory-bound: 512 MB HBM traffic -> ~85 us floor at 6.3 TB/s.

__device__ __forceinline__ float k1f(float x) {
    float rcp = __frcp_rn(x);              // 1/x, used by both branches

    // ---- small branch (x <= 2): A&S 9.8.7 ----
    float xh = x * 0.5f;
    float t  = xh * xh;                    // (x/2)^2
    float xi = x * (1.0f / 3.75f);
    float t2 = xi * xi;                    // (x/3.75)^2

    // I1 small-series poly (lowest degree first in ref; Horner from top)
    float p1 = 0.00032411f;
    p1 = fmaf(p1, t2, 0.00301532f);
    p1 = fmaf(p1, t2, 0.02658733f);
    p1 = fmaf(p1, t2, 0.15084934f);
    p1 = fmaf(p1, t2, 0.51498869f);
    p1 = fmaf(p1, t2, 0.87890594f);
    p1 = fmaf(p1, t2, 0.5f);
    float i1 = x * p1;

    float p2 = -0.00004686f;
    p2 = fmaf(p2, t, -0.00110404f);
    p2 = fmaf(p2, t, -0.01919402f);
    p2 = fmaf(p2, t, -0.18156897f);
    p2 = fmaf(p2, t, -0.67278579f);
    p2 = fmaf(p2, t, 0.15443144f);
    p2 = fmaf(p2, t, 1.0f);
    float small = fmaf(__logf(xh), i1, p2 * rcp);

    // ---- large branch (x > 2): A&S 9.8.8 ----
    float w = 2.0f * rcp;
    float p3 = -0.00068245f;
    p3 = fmaf(p3, w, 0.00325614f);
    p3 = fmaf(p3, w, -0.00780353f);
    p3 = fmaf(p3, w, 0.01504268f);
    p3 = fmaf(p3, w, -0.03655620f);
    p3 = fmaf(p3, w, 0.23498619f);
    p3 = fmaf(p3, w, 1.25331414f);
    float large = __expf(-x) * __frsqrt_rn(x) * p3;

    return (x <= 2.0f) ? small : large;
}

__global__ void __launch_bounds__(256) k1_kernel(const float* __restrict__ in,
                                                 float* __restrict__ out,
                                                 int n4) {
    const float4* in4  = (const float4*)in;
    float4*       out4 = (float4*)out;
    int stride = gridDim.x * blockDim.x;
    for (int i = blockIdx.x * blockDim.x + threadIdx.x; i < n4; i += stride) {
        float4 v = in4[i];
        float4 r;
        r.x = k1f(v.x);
        r.y = k1f(v.y);
        r.z = k1f(v.z);
        r.w = k1f(v.w);
        out4[i] = r;
    }
}

extern "C" void kernel_launch(void* const* d_in, const int* in_sizes, int n_in,
                              void* d_out, int out_size, void* d_ws, size_t ws_size,
                              hipStream_t stream) {
    const float* in  = (const float*)d_in[0];
    float*       out = (float*)d_out;
    int n  = in_sizes[0];          // 8192*8192, divisible by 4
    int n4 = n >> 2;
    int threads = 256;
    int blocks  = 8192;            // 256 CUs * 32 blocks; grid-stride covers rest
    k1_kernel<<<blocks, threads, 0, stream>>>(in, out, n4);
}

// Round 2
// 428.765 us; speedup vs baseline: 1.0063x; 1.0063x over previous
//
#include <hip/hip_runtime.h>

// Elementwise modified Bessel K_1(x), fp32, A&S 9.8.7 / 9.8.8.
// Memory-bound target: 512 MB HBM traffic -> ~80 us at 6.4 TB/s measured.
// Raw HW transcendentals (v_rcp/v_rsq/v_log/v_exp, ~1 ulp) — accuracy
// headroom is 50x under the 0.1975 absmax threshold.

__device__ __forceinline__ float k1f(float x) {
    float rcp = __builtin_amdgcn_rcpf(x);      // v_rcp_f32: ~1ulp 1/x
    float lg2 = __builtin_amdgcn_logf(x);      // v_log_f32: log2(x)

    // ---- small branch (x <= 2): A&S 9.8.7 ----
    float x2 = x * x;
    float t  = 0.25f * x2;                     // (x/2)^2
    float t2 = x2 * (1.0f / (3.75f * 3.75f));  // (x/3.75)^2

    float p1 = 0.00032411f;
    p1 = fmaf(p1, t2, 0.00301532f);
    p1 = fmaf(p1, t2, 0.02658733f);
    p1 = fmaf(p1, t2, 0.15084934f);
    p1 = fmaf(p1, t2, 0.51498869f);
    p1 = fmaf(p1, t2, 0.87890594f);
    p1 = fmaf(p1, t2, 0.5f);
    float i1 = x * p1;                         // I1_small(x)

    float p2 = -0.00004686f;
    p2 = fmaf(p2, t, -0.00110404f);
    p2 = fmaf(p2, t, -0.01919402f);
    p2 = fmaf(p2, t, -0.18156897f);
    p2 = fmaf(p2, t, -0.67278579f);
    p2 = fmaf(p2, t, 0.15443144f);
    p2 = fmaf(p2, t, 1.0f);

    float lnxh  = (lg2 - 1.0f) * 0.69314718056f;   // log(x/2) = ln2*(log2 x - 1)
    float small = fmaf(lnxh, i1, p2 * rcp);

    // ---- large branch (x > 2): A&S 9.8.8 ----
    float w = 2.0f * rcp;
    float p3 = -0.00068245f;
    p3 = fmaf(p3, w, 0.00325614f);
    p3 = fmaf(p3, w, -0.00780353f);
    p3 = fmaf(p3, w, 0.01504268f);
    p3 = fmaf(p3, w, -0.03655620f);
    p3 = fmaf(p3, w, 0.23498619f);
    p3 = fmaf(p3, w, 1.25331414f);
    float e     = __builtin_amdgcn_exp2f(x * -1.44269504089f);  // exp(-x)
    float large = e * __builtin_amdgcn_rsqf(x) * p3;            // v_rsq_f32

    return (x <= 2.0f) ? small : large;
}

__global__ void __launch_bounds__(256) k1_kernel(const float* __restrict__ in,
                                                 float* __restrict__ out,
                                                 int n4) {
    const float4* in4  = (const float4*)in;
    float4*       out4 = (float4*)out;
    int stride = gridDim.x * blockDim.x;
    for (int i = blockIdx.x * blockDim.x + threadIdx.x; i < n4; i += stride) {
        float4 v = in4[i];
        float4 r;
        r.x = k1f(v.x);
        r.y = k1f(v.y);
        r.z = k1f(v.z);
        r.w = k1f(v.w);
        out4[i] = r;
    }
}

extern "C" void kernel_launch(void* const* d_in, const int* in_sizes, int n_in,
                              void* d_out, int out_size, void* d_ws, size_t ws_size,
                              hipStream_t stream) {
    const float* in  = (const float*)d_in[0];
    float*       out = (float*)d_out;
    int n  = in_sizes[0];          // 8192*8192, divisible by 4
    int n4 = n >> 2;
    int threads = 256;
    int blocks  = 8192;            // grid-stride, 8 float4 iters/thread
    k1_kernel<<<blocks, threads, 0, stream>>>(in, out, n4);
}